// Round 14
// baseline (50.917 us; speedup 1.0000x reference)
//
#include <hip/hip_runtime.h>

// RoutingLayer: capsule routing on MI355X (gfx950).
// n = 50000 nodes, D=128 = K=8 capsules x dd=16, M=20 neighbors, max_iter=3.
// Round 14 = round 13 (verified, 49.8 us) with routing blocks widened to
// 512 threads (8 waves/block, 8 nodes/block). Per-wave code byte-identical;
// occupancy was stuck at ~67% (~5.3 blocks/CU) with VGPR=24/LDS=5KB -> smells
// workgroup-slot-limited, not resource-limited. Halving block count per wave
// should raise resident waves and latency hiding.
// Ledger: r6-r9 4-node layout = wrong; r12 2-node ILP = regression;
// r11/r13 structure verified.

#define D   128
#define K   8
#define DD  16
#define M   20
#define WPB 8           // waves (= nodes) per routing block

typedef _Float16 h2 __attribute__((ext_vector_type(2)));
typedef unsigned int u32;

__device__ __forceinline__ h2 pack_h2(float a, float b) {
    return __builtin_bit_cast(h2, __builtin_amdgcn_cvt_pkrtz(a, b));
}

// builtin (compiler-managed hazards) DPP add
#define DPPADD(x, ctrl) ((x) + __int_as_float(__builtin_amdgcn_update_dpp( \
        0, __float_as_int(x), (ctrl), 0xF, 0xF, false)))

__device__ __forceinline__ float red8_b(float x) {    // sum over 8-lane group
    x = DPPADD(x, 0xB1); x = DPPADD(x, 0x4E); x = DPPADD(x, 0x141);
    return x;
}

// 4 independent 8-lane sum reductions, 1 inst per DPP add (r5/r10/r11-proven).
#define RED8_X4(a, b, c, d) \
  asm volatile( \
    "s_nop 1\n\t" \
    "v_add_f32_dpp %0, %0, %0 quad_perm:[1,0,3,2] row_mask:0xf bank_mask:0xf\n\t" \
    "v_add_f32_dpp %1, %1, %1 quad_perm:[1,0,3,2] row_mask:0xf bank_mask:0xf\n\t" \
    "v_add_f32_dpp %2, %2, %2 quad_perm:[1,0,3,2] row_mask:0xf bank_mask:0xf\n\t" \
    "v_add_f32_dpp %3, %3, %3 quad_perm:[1,0,3,2] row_mask:0xf bank_mask:0xf\n\t" \
    "v_add_f32_dpp %0, %0, %0 quad_perm:[2,3,0,1] row_mask:0xf bank_mask:0xf\n\t" \
    "v_add_f32_dpp %1, %1, %1 quad_perm:[2,3,0,1] row_mask:0xf bank_mask:0xf\n\t" \
    "v_add_f32_dpp %2, %2, %2 quad_perm:[2,3,0,1] row_mask:0xf bank_mask:0xf\n\t" \
    "v_add_f32_dpp %3, %3, %3 quad_perm:[2,3,0,1] row_mask:0xf bank_mask:0xf\n\t" \
    "v_add_f32_dpp %0, %0, %0 row_half_mirror row_mask:0xf bank_mask:0xf\n\t" \
    "v_add_f32_dpp %1, %1, %1 row_half_mirror row_mask:0xf bank_mask:0xf\n\t" \
    "v_add_f32_dpp %2, %2, %2 row_half_mirror row_mask:0xf bank_mask:0xf\n\t" \
    "v_add_f32_dpp %3, %3, %3 row_half_mirror row_mask:0xf bank_mask:0xf" \
    : "+v"(a), "+v"(b), "+v"(c), "+v"(d))

__device__ __forceinline__ float dot2(u32 za, h2 ub) {
#if __has_builtin(__builtin_amdgcn_fdot2)
    return __builtin_amdgcn_fdot2(__builtin_bit_cast(h2, za), ub, 0.0f, false);
#else
    h2 ah = __builtin_bit_cast(h2, za);
    return fmaf((float)ah.x, (float)ub.x, (float)ah.y * (float)ub.y);
#endif
}

// Vectorized per-capsule L2 normalize into packed-f16 table (r13-verified).
// One thread per dim-pair: float2 load (8B/lane), red8_b capsule reduce,
// one u32 store. Pad row appended at [totalPairs, totalPairs+64).
__global__ __launch_bounds__(256) void prenorm2_kernel(const float* __restrict__ in,
                                                       u32* __restrict__ tab,
                                                       int totalPairs) {
    int i = blockIdx.x * 256 + threadIdx.x;          // pair index
    float2 v = make_float2(0.0f, 0.0f);
    if (i < totalPairs) v = ((const float2*)in)[i];  // totalPairs % 8 == 0
    float ss = red8_b(v.x * v.x + v.y * v.y);
    float inv = (ss > 0.0f) ? rsqrtf(ss) : 0.0f;     // zero row -> 0 (ref 0/eps)
    if (i < totalPairs + D / 2)
        tab[i] = __builtin_bit_cast(u32, pack_h2(v.x * inv, v.y * inv));
}

template<bool PRE>
__global__ __launch_bounds__(WPB * 64) void routing_kernel(
    const _Float16* __restrict__ tab,  // PRE: [(n+1)*128] normalized fp16, row n = 0
    const float*    __restrict__ raw,  // !PRE: raw fp32 input
    const int*      __restrict__ nbr,  // [n*20]
    const int*      __restrict__ maxit_p,
    float*          __restrict__ out,  // [n,128] fp32
    int n)
{
    const int t  = threadIdx.x;
    const int wv = t >> 6;                 // wave slot in block (0..WPB-1)
    const int l  = t & 63;                 // lane; owns dims (2l, 2l+1)
    const int node = blockIdx.x * WPB + wv;
    const int myk  = l >> 3;               // capsule 0..7 (8 lanes each)
    if (node >= n) return;
    const int max_iter = maxit_p[0];
    const int nodeu = __builtin_amdgcn_readfirstlane(node);

    __shared__ float p_lds[WPB][M][K];     // logits (f32)
    __shared__ u32   w_lds[WPB][M][K];     // packed h2{w,w} weights

    // neighbor ids via scalar pipe (uniform address -> s_load)
    int ids[M];
    {
        const int* nrow = nbr + nodeu * M;
        #pragma unroll
        for (int mm = 0; mm < M; ++mm) ids[mm] = nrow[mm] + nodeu * 5;  // in [0,n]
    }

    // own x + gathered z rows, packed f16 pairs
    u32 z[M];
    h2  xh;                                // own normalized x, packed f16
    if (PRE) {
        const u32* t32 = (const u32*)tab;
        xh = __builtin_bit_cast(h2, t32[(size_t)nodeu * (D / 2) + l]);
        #pragma unroll
        for (int mm = 0; mm < M; ++mm)
            z[mm] = t32[(size_t)ids[mm] * (D / 2) + l];   // row n is zeros
    } else {
        const float2* r2 = (const float2*)raw;
        float2 x0 = r2[(size_t)nodeu * (D / 2) + l];
        float s = red8_b(x0.x * x0.x + x0.y * x0.y);
        float inv = (s > 0.0f) ? rsqrtf(s) : 0.0f;
        xh = pack_h2(x0.x * inv, x0.y * inv);
        #pragma unroll
        for (int mm = 0; mm < M; ++mm) {
            float2 zv = (ids[mm] < n) ? r2[(size_t)ids[mm] * (D / 2) + l]
                                      : make_float2(0.f, 0.f);
            float s2 = red8_b(zv.x * zv.x + zv.y * zv.y);
            float i2 = (s2 > 0.0f) ? rsqrtf(s2) : 0.0f;
            z[mm] = __builtin_bit_cast(u32, pack_h2(zv.x * i2, zv.y * i2));
        }
    }

    // ---- iteration 0: p = softmax(0) = 1/K; u = x + 0.125 * sum_m z ----
    const h2 kEighth = pack_h2(0.125f, 0.125f);
    h2 u = xh;
    #pragma unroll
    for (int mm = 0; mm < M; ++mm)
        u = __builtin_bit_cast(h2, z[mm]) * kEighth + u;   // v_pk_fma_f16
    if (max_iter > 1) {
        float s = red8_b(dot2(__builtin_bit_cast(u32, u), u));  // sum u^2 over capsule
        float inv = (s > 0.0f) ? rsqrtf(s) : 0.0f;
        h2 invh = pack_h2(inv, inv);
        u = u * invh;                                      // v_pk_mul_f16
    }

    // ---- iterations 1..max_iter-1 (intra-wave only) ----
    for (int it = 1; it < max_iter; ++it) {
        // phase 1: capsule dots -> p_lds (r5/r10-proven)
        #pragma unroll
        for (int mm = 0; mm < M; mm += 4) {
            float p0 = dot2(z[mm + 0], u);
            float p1 = dot2(z[mm + 1], u);
            float p2 = dot2(z[mm + 2], u);
            float p3 = dot2(z[mm + 3], u);
            RED8_X4(p0, p1, p2, p3);             // all 8 lanes hold each sum
            if ((l & 7) == 0) {
                p_lds[wv][mm + 0][myk] = p0;
                p_lds[wv][mm + 1][myk] = p1;
                p_lds[wv][mm + 2][myk] = p2;
                p_lds[wv][mm + 3][myk] = p3;
            }
        }
        __builtin_amdgcn_wave_barrier();

        // phase 2: lane-parallel softmax (r10-proven), storing packed h2{w,w}.
        // Lane l handles (m = base + (l>>3), k = l&7); 3 passes; no max-sub
        // (|p|<=1 for unit vectors); S via red8_b; w = e * rcp(S).
        #pragma unroll
        for (int base = 0; base < M; base += 8) {
            int mm = base + (l >> 3);
            int mc = (mm < M) ? mm : (M - 1);          // clamp keeps all lanes live
            float e = __expf(p_lds[wv][mc][l & 7]);
            float S = red8_b(e);                        // sum over k within 8-group
            float w = e * __builtin_amdgcn_rcpf(S);
            if (mm < M)
                w_lds[wv][mm][l & 7] = __builtin_bit_cast(u32, pack_h2(w, w));
        }
        __builtin_amdgcn_wave_barrier();

        // phase 3: PV accumulate, packed f16 (1 v_pk_fma_f16 per m)
        h2 unew = xh;
        #pragma unroll
        for (int mm = 0; mm < M; ++mm) {
            h2 w2 = __builtin_bit_cast(h2, w_lds[wv][mm][myk]);
            unew = __builtin_bit_cast(h2, z[mm]) * w2 + unew;
        }
        u = unew;
        if (it < max_iter - 1) {
            float s = red8_b(dot2(__builtin_bit_cast(u32, u), u));
            float inv = (s > 0.0f) ? rsqrtf(s) : 0.0f;
            h2 invh = pack_h2(inv, inv);
            u = u * invh;
        }
        __builtin_amdgcn_wave_barrier();           // keep next p-writes behind w-reads
    }

    // ---- store: unpack h2 -> f32 pair, coalesced float2 ----
    float2* o2 = (float2*)out;
    o2[(size_t)node * (D / 2) + l] = make_float2((float)u.x, (float)u.y);
}

extern "C" void kernel_launch(void* const* d_in, const int* in_sizes, int n_in,
                              void* d_out, int out_size, void* d_ws, size_t ws_size,
                              hipStream_t stream) {
    const float* in  = (const float*)d_in[0];
    const int*   nbr = (const int*)d_in[1];
    const int*   mit = (const int*)d_in[2];
    float*       out = (float*)d_out;

    const int n     = in_sizes[0] / D;    // 50000
    const int total = n * D;
    const int nblk  = (n + WPB - 1) / WPB;

    if (ws_size >= (size_t)(total + D) * sizeof(_Float16)) {
        _Float16* tab = (_Float16*)d_ws;
        const int totalPairs = total / 2;                 // 3,200,000 (mult of 8)
        const int tblk = (totalPairs + D / 2 + 255) / 256;
        prenorm2_kernel<<<tblk, 256, 0, stream>>>(in, (u32*)tab, totalPairs);
        routing_kernel<true><<<nblk, WPB * 64, 0, stream>>>(tab, nullptr, nbr, mit, out, n);
    } else {
        routing_kernel<false><<<nblk, WPB * 64, 0, stream>>>(nullptr, in, nbr, mit, out, n);
    }
}